// Round 21
// baseline (74.318 us; speedup 1.0000x reference)
//
#include <hip/hip_runtime.h>

namespace {

constexpr int NB = 8, NP = 8192, NC = 91;
constexpr int KTOP = 1000, NDET = 100;
constexpr int MROWS = 1024;
constexpr int NBUCK = 4096, SORTN = 4096;
constexpr int NLAB = 90;             // classes 1..90
constexpr int BPI = 512;             // candidate blocks per image
constexpr int BCAP = 304;            // 16 proposals * <=19 candidates (softmax bound)
constexpr float SCORE_T = 0.05f;
constexpr float MIN_SZ = 0.01f;
constexpr float NMS_T = 0.5f;
constexpr float CLIPV = 4.135166556742356f;  // log(1000/16)
constexpr float NEGV = -1e9f;

typedef unsigned long long ull;

__device__ __forceinline__ void decode_box(const float4& pr, const float4& rel,
                                           float Wf, float Hf,
                                           float& x1, float& y1, float& x2, float& y2) {
  float w = pr.z - pr.x, h = pr.w - pr.y;
  float cx = pr.x + 0.5f * w, cy = pr.y + 0.5f * h;
  float dx = rel.x / 10.0f, dy = rel.y / 10.0f;
  float dw = fminf(rel.z / 5.0f, CLIPV), dh = fminf(rel.w / 5.0f, CLIPV);
  float pcx = dx * w + cx, pcy = dy * h + cy;
  float pw = expf(dw) * w, ph = expf(dh) * h;
  x1 = fminf(fmaxf(pcx - 0.5f * pw, 0.0f), Wf);
  y1 = fminf(fmaxf(pcy - 0.5f * ph, 0.0f), Hf);
  x2 = fminf(fmaxf(pcx + 0.5f * pw, 0.0f), Wf);
  y2 = fminf(fmaxf(pcy + 0.5f * ph, 0.0f), Hf);
}

__device__ __forceinline__ int score_bucket(unsigned bits) {
  return min((int)((bits - 0x3D000000u) >> 14), NBUCK - 1);
}

// 16-lane group per proposal; 16 proposals per 256-thread block, logits staged
// through 5.8KB LDS. Logit-domain prefilter (strict superset, -1e-3 margin)
// gates the exact score test. Deterministic per-block 304-slot segment +
// unconditional bcnt[bid] store: no atomics, no memset. (verbatim R18)
__global__ __launch_bounds__(256) void k_candidates(
    const float* __restrict__ logits, const float* __restrict__ boxreg,
    const float* __restrict__ props, const int* __restrict__ hw,
    ull* __restrict__ dense, int* __restrict__ bcnt) {
  __shared__ float sh[16 * NC];
  __shared__ ull stage[16][20];
  __shared__ int gcnt[16];
  __shared__ int gbase[16];
  int tid = threadIdx.x;
  int base = blockIdx.x * 16;
  const float4* src4 = reinterpret_cast<const float4*>(logits + (size_t)base * NC);
  float4* sh4 = reinterpret_cast<float4*>(sh);
  for (int i = tid; i < (16 * NC) / 4; i += 256) sh4[i] = src4[i];
  __syncthreads();

  int lane = tid & 63;
  int l16 = lane & 15;
  int grp = lane >> 4;
  int wv = tid >> 6;
  int lp = wv * 4 + grp;
  int gw = base + lp;
  int p = gw & (NP - 1);
  float Hf = (float)hw[0], Wf = (float)hw[1];
  const float* row = sh + lp * NC;

  float zreg[6];
  float m = -3.0e38f;
#pragma unroll
  for (int k = 0; k < 6; ++k) {
    int c = k * 16 + l16;
    float z = (c < NC) ? row[c] : -3.0e38f;
    zreg[k] = z;
    m = fmaxf(m, z);
  }
#pragma unroll
  for (int d = 1; d < 16; d <<= 1) m = fmaxf(m, __shfl_xor(m, d, 64));
  float S = 0.0f;
#pragma unroll
  for (int k = 0; k < 6; ++k) {
    int c = k * 16 + l16;
    S += (c < NC) ? expf(zreg[k] - m) : 0.0f;
  }
#pragma unroll
  for (int d = 1; d < 16; d <<= 1) S += __shfl_xor(S, d, 64);

  float invS = 1.0f / S;
  float thr = m + logf(SCORE_T * S) - 1e-3f;   // superset prefilter

  float4 pr = reinterpret_cast<const float4*>(props)[gw];
  const float4* relrow = reinterpret_cast<const float4*>(boxreg + (size_t)gw * 4 * NC);
  unsigned below = (1u << l16) - 1u;
  int n = 0;
#pragma unroll
  for (int k = 0; k < 6; ++k) {
    int c = k * 16 + l16;
    bool ok = (c >= 1) && (c < NC) && (zreg[k] > thr);
    float sc = 0.0f;
    if (ok) {
      sc = expf(zreg[k] - m) * invS;
      ok = sc > SCORE_T;
      if (ok) {
        float4 rel = relrow[c];
        float x1, y1, x2, y2;
        decode_box(pr, rel, Wf, Hf, x1, y1, x2, y2);
        ok = ((x2 - x1) >= MIN_SZ) && ((y2 - y1) >= MIN_SZ);
      }
    }
    ull bal = __ballot(ok);
    unsigned gm = (unsigned)((bal >> (grp * 16)) & 0xFFFFull);
    if (ok) {
      int pos = n + __popc(gm & below);
      unsigned bits = __float_as_uint(sc);
      int idx = p * (NC - 1) + (c - 1);
      if (pos < 20) stage[lp][pos] = ((ull)bits << 32) | (unsigned)(~(unsigned)idx);
    }
    n += __popc(gm);
  }
  if (l16 == 0) gcnt[lp] = min(n, 20);
  __syncthreads();
  if (tid == 0) {
    int off[16];
    int tot = 0;
#pragma unroll
    for (int g = 0; g < 16; ++g) { off[g] = tot; tot += gcnt[g]; }
#pragma unroll
    for (int g = 0; g < 16; ++g) gbase[g] = off[g];
    bcnt[blockIdx.x] = tot;                  // unconditional -> no memset needed
  }
  __syncthreads();
  ull* dst = dense + (size_t)blockIdx.x * BCAP;
  for (int j = l16; j < gcnt[lp]; j += 16) dst[gbase[lp] + j] = stage[lp][j];
}

// Fused per-image selection on deterministic dense segments (verbatim R18,
// plus: zeroes done[b] for the nms+emit kernel's completion counters).
__global__ __launch_bounds__(1024) void k_select(
    const ull* __restrict__ dense, const int* __restrict__ bcnt,
    const float* __restrict__ boxreg, const float* __restrict__ props,
    const int* __restrict__ hw,
    float* __restrict__ topk_score, float* __restrict__ det_box,
    int* __restrict__ det_label, int* __restrict__ keep, int* __restrict__ nvalid,
    int* __restrict__ done) {
  __shared__ int h[NBUCK];                   // 16KB
  __shared__ int cur[NBUCK];                 // 16KB
  __shared__ ull sk[SORTN];                  // 32KB
  __shared__ int sbs;
  int b = blockIdx.x, tid = threadIdx.x;
#pragma unroll
  for (int k = 0; k < NBUCK / 1024; ++k) h[tid + k * 1024] = 0;
  if (tid == 0) { sbs = 0; done[b] = 0; }    // reset completion counter per launch
  __syncthreads();
  int seg = tid >> 1;                        // 512 segments per image
  int par = tid & 1;
  int gseg = b * BPI + seg;
  int scnt = bcnt[gseg];
  const ull* sptr = dense + (size_t)gseg * BCAP;
  // pass A: histogram
  for (int j = par; j < scnt; j += 2)
    atomicAdd(&h[score_bucket((unsigned)(sptr[j] >> 32))], 1);
  __syncthreads();
  // inclusive suffix scan: h[i] = count in buckets >= i
  for (int d = 1; d < NBUCK; d <<= 1) {
    int v[NBUCK / 1024];
#pragma unroll
    for (int k = 0; k < NBUCK / 1024; ++k) {
      int i = tid + k * 1024;
      v[k] = h[i] + ((i + d < NBUCK) ? h[i + d] : 0);
    }
    __syncthreads();
#pragma unroll
    for (int k = 0; k < NBUCK / 1024; ++k) h[tid + k * 1024] = v[k];
    __syncthreads();
  }
#pragma unroll
  for (int k = 0; k < NBUCK / 1024; ++k) {
    int i = tid + k * 1024;
    if (h[i] >= KTOP && (i == NBUCK - 1 || h[i + 1] < KTOP)) sbs = i;
  }
  __syncthreads();
#pragma unroll
  for (int k = 0; k < NBUCK / 1024; ++k) {
    int i = tid + k * 1024;
    cur[i] = (i + 1 < NBUCK) ? h[i + 1] : 0;   // region starts -> working cursors
  }
  __syncthreads();
  int sb = sbs;
  int total = min(h[sb], SORTN);
  // pass B: scatter survivors into sk at per-bucket LDS cursors
  for (int j = par; j < scnt; j += 2) {
    ull key = sptr[j];
    int bk = score_bucket((unsigned)(key >> 32));
    if (bk < sb) continue;
    int pos = atomicAdd(&cur[bk], 1);
    if (pos < SORTN) sk[pos] = key;
  }
  __syncthreads();
  // segmented rank + decode + keep init
  float Hf = (float)hw[0], Wf = (float)hw[1];
  for (int i = tid; i < total; i += 1024) {
    ull key = sk[i];
    int bk = score_bucket((unsigned)(key >> 32));
    int s0 = (bk + 1 < NBUCK) ? h[bk + 1] : 0;
    int e = min(cur[bk], total);
    int r = s0;
    for (int j = s0; j < e; ++j) r += (sk[j] > key) ? 1 : 0;
    if (r < KTOP) {
      int og = b * KTOP + r;
      topk_score[og] = __uint_as_float((unsigned)(key >> 32));
      int fidx = (int)(~(unsigned)key);
      int p = fidx / (NC - 1), c = fidx % (NC - 1) + 1;
      float4 pr = reinterpret_cast<const float4*>(props)[b * NP + p];
      float4 rel =
          reinterpret_cast<const float4*>(boxreg + (size_t)(b * NP + p) * 4 * NC)[c];
      float x1, y1, x2, y2;
      decode_box(pr, rel, Wf, Hf, x1, y1, x2, y2);
      det_box[(size_t)og * 4 + 0] = x1;
      det_box[(size_t)og * 4 + 1] = y1;
      det_box[(size_t)og * 4 + 2] = x2;
      det_box[(size_t)og * 4 + 3] = y2;
      det_label[og] = c;
      keep[og] = 1;
    }
  }
  int valid_n = min(total, KTOP);
  for (int r = valid_n + tid; r < KTOP; r += 1024) {
    int og = b * KTOP + r;
    topk_score[og] = NEGV;
    det_box[(size_t)og * 4 + 0] = 0.0f;
    det_box[(size_t)og * 4 + 1] = 0.0f;
    det_box[(size_t)og * 4 + 2] = 0.0f;
    det_box[(size_t)og * 4 + 3] = 0.0f;
    det_label[og] = 0;
    keep[og] = 0;
  }
  if (tid == 0) nvalid[b] = valid_n;
}

// WIDE per-(image,label) greedy NMS (720 one-wave blocks) + fused emit:
// every block releases its keep stores (__threadfence) then increments the
// per-image done counter (device-scope atomic); the LAST block per image
// acquires (__threadfence) and emits that image's first 100 kept via 16x64
// ballot-compaction over keep (exact sorted positions), then zero-pads.
__global__ __launch_bounds__(64) void k_nmsout(
    const int* __restrict__ nvalid, const float* __restrict__ topk_score,
    const float* __restrict__ det_box, const int* __restrict__ det_label,
    int* __restrict__ keep, int* __restrict__ done, float* __restrict__ out) {
  __shared__ int list[MROWS];
  __shared__ float4 mbx[64];
  __shared__ unsigned char sup[MROWS];
  int bb = blockIdx.x;
  int b = bb / NLAB;
  int lab = bb % NLAB + 1;
  int lane = threadIdx.x;
  int nv = nvalid[b];
  ull below = (1ull << lane) - 1ull;
  const int* ll = det_label + b * KTOP;
  const float4* bbx = reinterpret_cast<const float4*>(det_box) + (size_t)b * KTOP;
  int c = 0;
  for (int base = 0; base < KTOP; base += 64) {
    int i = base + lane;
    bool mb = (i < KTOP) && (i < nv) && (ll[i] == lab);
    ull bal = __ballot(mb);
    if (mb) list[c + __popcll(bal & below)] = i;
    c += __popcll(bal);
  }
  if (c > 1) {
    __syncthreads();
    if (c <= 64) {
      if (lane < c) mbx[lane] = bbx[list[lane]];
      __syncthreads();
      float4 bx = mbx[(lane < c) ? lane : 0];
      float area = (bx.z - bx.x) * (bx.w - bx.y);
      ull col = 0ull;
      for (int i = 0; i + 1 < c; ++i) {
        float4 bi = mbx[i];                    // uniform -> broadcast, independent
        float ai = (bi.z - bi.x) * (bi.w - bi.y);
        float ltx = fmaxf(bi.x, bx.x), lty = fmaxf(bi.y, bx.y);
        float rbx = fminf(bi.z, bx.z), rby = fminf(bi.w, bx.w);
        float iw = fmaxf(rbx - ltx, 0.0f), ih = fmaxf(rby - lty, 0.0f);
        float inter = iw * ih;
        float iou = inter / (ai + area - inter + 1e-9f);
        if ((lane > i) && (lane < c) && (iou > NMS_T)) col |= (1ull << i);
      }
      if (__ballot(col != 0ull)) {
        unsigned s = 0u;
        for (int i = 0; i + 1 < c; ++i) {
          ull act = __ballot(s == 0u);         // bit i final at step i
          s |= (unsigned)((act >> i) & (col >> i) & 1ull);
        }
        if (lane < c && s) keep[b * KTOP + list[lane]] = 0;
      }
    } else if (lane == 0) {
      // pathological big group: ordered serial greedy on lane 0 (rarely hit)
      for (int a = 0; a < c; ++a) sup[a] = 0;
      for (int a = 0; a < c; ++a) {
        if (sup[a]) continue;
        float4 bi = bbx[list[a]];
        float ai = (bi.z - bi.x) * (bi.w - bi.y);
        for (int e = a + 1; e < c; ++e) {
          if (sup[e]) continue;
          float4 bj = bbx[list[e]];
          float aj = (bj.z - bj.x) * (bj.w - bj.y);
          float ltx = fmaxf(bi.x, bj.x), lty = fmaxf(bi.y, bj.y);
          float rbx = fminf(bi.z, bj.z), rby = fminf(bi.w, bj.w);
          float iw = fmaxf(rbx - ltx, 0.0f), ih = fmaxf(rby - lty, 0.0f);
          float inter = iw * ih;
          if (inter / (ai + aj - inter + 1e-9f) > NMS_T) sup[e] = 1;
        }
      }
      for (int a = 0; a < c; ++a)
        if (sup[a]) keep[b * KTOP + list[a]] = 0;
    }
  }
  // ---- completion + fused emit (ALL blocks reach here; no early returns) ----
  __syncthreads();
  __threadfence();                            // release keep stores (device scope)
  __shared__ int prev_sh;
  if (lane == 0) prev_sh = atomicAdd(&done[b], 1);
  __syncthreads();
  if (prev_sh == NLAB - 1) {
    __threadfence();                          // acquire other blocks' keep stores
    const int* kp = keep + b * KTOP;
    float* ob = out;
    float* os = out + (size_t)NB * NDET * 4;
    float* ol = os + (size_t)NB * NDET;
    int base2 = 0;
    for (int ch = 0; ch < 16; ++ch) {
      int i = ch * 64 + lane;
      int k = (i < KTOP) ? kp[i] : 0;
      ull bal = __ballot(k != 0);
      if (k) {
        int r = base2 + __popcll(bal & below);
        if (r < NDET) {
          float4 bx = bbx[i];
          ob[((size_t)b * NDET + r) * 4 + 0] = bx.x;
          ob[((size_t)b * NDET + r) * 4 + 1] = bx.y;
          ob[((size_t)b * NDET + r) * 4 + 2] = bx.z;
          ob[((size_t)b * NDET + r) * 4 + 3] = bx.w;
          os[b * NDET + r] = topk_score[b * KTOP + i];
          ol[b * NDET + r] = (float)ll[i];
        }
      }
      base2 += __popcll(bal);
    }
    int total = min(base2, NDET);
    for (int r = total + lane; r < NDET; r += 64) {
      ob[((size_t)b * NDET + r) * 4 + 0] = 0.0f;
      ob[((size_t)b * NDET + r) * 4 + 1] = 0.0f;
      ob[((size_t)b * NDET + r) * 4 + 2] = 0.0f;
      ob[((size_t)b * NDET + r) * 4 + 3] = 0.0f;
      os[b * NDET + r] = 0.0f;
      ol[b * NDET + r] = 0.0f;
    }
  }
}

}  // namespace

extern "C" void kernel_launch(void* const* d_in, const int* in_sizes, int n_in,
                              void* d_out, int out_size, void* d_ws, size_t ws_size,
                              hipStream_t stream) {
  const float* logits = (const float*)d_in[0];
  const float* boxreg = (const float*)d_in[1];
  const float* props = (const float*)d_in[2];
  const int* hw = (const int*)d_in[3];

  char* ws = (char*)d_ws;
  size_t off = 0;
  auto alloc = [&](size_t bytes) -> void* {
    void* p = ws + off;
    off += (bytes + 255) & ~(size_t)255;
    return p;
  };
  ull* dense = (ull*)alloc((size_t)NB * BPI * BCAP * 8);
  int* bcnt = (int*)alloc((size_t)NB * BPI * 4);
  float* topk_score = (float*)alloc((size_t)NB * KTOP * 4);
  float* det_box = (float*)alloc((size_t)NB * KTOP * 16);
  int* det_label = (int*)alloc((size_t)NB * KTOP * 4);
  int* keep = (int*)alloc((size_t)NB * KTOP * 4);
  int* nvalid = (int*)alloc(NB * 4);
  int* done = (int*)alloc(NB * 4);

  k_candidates<<<(NB * NP) / 16, 256, 0, stream>>>(logits, boxreg, props, hw,
                                                   dense, bcnt);
  k_select<<<NB, 1024, 0, stream>>>(dense, bcnt, boxreg, props, hw,
                                    topk_score, det_box, det_label, keep, nvalid,
                                    done);
  k_nmsout<<<NB * NLAB, 64, 0, stream>>>(nvalid, topk_score, det_box, det_label,
                                         keep, done, (float*)d_out);
}

// Round 22
// 62.400 us; speedup vs baseline: 1.1910x; 1.1910x over previous
//
#include <hip/hip_runtime.h>

namespace {

constexpr int NB = 8, NP = 8192, NC = 91;
constexpr int KTOP = 1000, NDET = 100;
constexpr int MROWS = 1024;
constexpr int NBUCK = 4096, SORTN = 4096;
constexpr int NLAB = 90;             // classes 1..90
constexpr int BPI = 512;             // candidate blocks per image
constexpr int BCAP = 304;            // 16 proposals * <=19 candidates (softmax bound)
constexpr float SCORE_T = 0.05f;
constexpr float MIN_SZ = 0.01f;
constexpr float NMS_T = 0.5f;
constexpr float CLIPV = 4.135166556742356f;  // log(1000/16)
constexpr float NEGV = -1e9f;

typedef unsigned long long ull;

__device__ __forceinline__ void decode_box(const float4& pr, const float4& rel,
                                           float Wf, float Hf,
                                           float& x1, float& y1, float& x2, float& y2) {
  float w = pr.z - pr.x, h = pr.w - pr.y;
  float cx = pr.x + 0.5f * w, cy = pr.y + 0.5f * h;
  float dx = rel.x / 10.0f, dy = rel.y / 10.0f;
  float dw = fminf(rel.z / 5.0f, CLIPV), dh = fminf(rel.w / 5.0f, CLIPV);
  float pcx = dx * w + cx, pcy = dy * h + cy;
  float pw = expf(dw) * w, ph = expf(dh) * h;
  x1 = fminf(fmaxf(pcx - 0.5f * pw, 0.0f), Wf);
  y1 = fminf(fmaxf(pcy - 0.5f * ph, 0.0f), Hf);
  x2 = fminf(fmaxf(pcx + 0.5f * pw, 0.0f), Wf);
  y2 = fminf(fmaxf(pcy + 0.5f * ph, 0.0f), Hf);
}

__device__ __forceinline__ int score_bucket(unsigned bits) {
  return min((int)((bits - 0x3D000000u) >> 14), NBUCK - 1);
}

// 16-lane group per proposal; 16 proposals per 256-thread block, logits staged
// through 5.8KB LDS. Logit-domain prefilter (strict superset, -1e-3 margin)
// gates the exact score test. Candidates staged in LDS then written to a
// DETERMINISTIC per-block 304-slot segment + unconditional bcnt[bid] store:
// no atomics, no memset. Order is block-deterministic; downstream rank on
// unique keys is order-independent anyway.
__global__ __launch_bounds__(256) void k_candidates(
    const float* __restrict__ logits, const float* __restrict__ boxreg,
    const float* __restrict__ props, const int* __restrict__ hw,
    ull* __restrict__ dense, int* __restrict__ bcnt) {
  __shared__ float sh[16 * NC];
  __shared__ ull stage[16][20];
  __shared__ int gcnt[16];
  __shared__ int gbase[16];
  int tid = threadIdx.x;
  int base = blockIdx.x * 16;
  const float4* src4 = reinterpret_cast<const float4*>(logits + (size_t)base * NC);
  float4* sh4 = reinterpret_cast<float4*>(sh);
  for (int i = tid; i < (16 * NC) / 4; i += 256) sh4[i] = src4[i];
  __syncthreads();

  int lane = tid & 63;
  int l16 = lane & 15;
  int grp = lane >> 4;
  int wv = tid >> 6;
  int lp = wv * 4 + grp;
  int gw = base + lp;
  int p = gw & (NP - 1);
  float Hf = (float)hw[0], Wf = (float)hw[1];
  const float* row = sh + lp * NC;

  float zreg[6];
  float m = -3.0e38f;
#pragma unroll
  for (int k = 0; k < 6; ++k) {
    int c = k * 16 + l16;
    float z = (c < NC) ? row[c] : -3.0e38f;
    zreg[k] = z;
    m = fmaxf(m, z);
  }
#pragma unroll
  for (int d = 1; d < 16; d <<= 1) m = fmaxf(m, __shfl_xor(m, d, 64));
  float S = 0.0f;
#pragma unroll
  for (int k = 0; k < 6; ++k) {
    int c = k * 16 + l16;
    S += (c < NC) ? expf(zreg[k] - m) : 0.0f;
  }
#pragma unroll
  for (int d = 1; d < 16; d <<= 1) S += __shfl_xor(S, d, 64);

  float invS = 1.0f / S;
  float thr = m + logf(SCORE_T * S) - 1e-3f;   // superset prefilter

  float4 pr = reinterpret_cast<const float4*>(props)[gw];
  const float4* relrow = reinterpret_cast<const float4*>(boxreg + (size_t)gw * 4 * NC);
  unsigned below = (1u << l16) - 1u;
  int n = 0;
#pragma unroll
  for (int k = 0; k < 6; ++k) {
    int c = k * 16 + l16;
    bool ok = (c >= 1) && (c < NC) && (zreg[k] > thr);
    float sc = 0.0f;
    if (ok) {
      sc = expf(zreg[k] - m) * invS;
      ok = sc > SCORE_T;
      if (ok) {
        float4 rel = relrow[c];
        float x1, y1, x2, y2;
        decode_box(pr, rel, Wf, Hf, x1, y1, x2, y2);
        ok = ((x2 - x1) >= MIN_SZ) && ((y2 - y1) >= MIN_SZ);
      }
    }
    ull bal = __ballot(ok);
    unsigned gm = (unsigned)((bal >> (grp * 16)) & 0xFFFFull);
    if (ok) {
      int pos = n + __popc(gm & below);
      unsigned bits = __float_as_uint(sc);
      int idx = p * (NC - 1) + (c - 1);
      if (pos < 20) stage[lp][pos] = ((ull)bits << 32) | (unsigned)(~(unsigned)idx);
    }
    n += __popc(gm);
  }
  if (l16 == 0) gcnt[lp] = min(n, 20);
  __syncthreads();
  if (tid == 0) {
    int off[16];
    int tot = 0;
#pragma unroll
    for (int g = 0; g < 16; ++g) { off[g] = tot; tot += gcnt[g]; }
#pragma unroll
    for (int g = 0; g < 16; ++g) gbase[g] = off[g];
    bcnt[blockIdx.x] = tot;                  // unconditional -> no memset needed
  }
  __syncthreads();
  ull* dst = dense + (size_t)blockIdx.x * BCAP;
  for (int j = l16; j < gcnt[lp]; j += 16) dst[gbase[lp] + j] = stage[lp][j];
}

// Fused per-image selection on deterministic dense segments: 2 threads per
// segment (parity-interleaved, ~15 independent pipelined loads each) for the
// histogram and scatter passes; LDS suffix scan -> threshold bucket ->
// segmented rank (position = region_start + #greater region-mates; unique
// keys -> bijective) -> decode + keep init + tail pad. One block per image.
__global__ __launch_bounds__(1024) void k_select(
    const ull* __restrict__ dense, const int* __restrict__ bcnt,
    const float* __restrict__ boxreg, const float* __restrict__ props,
    const int* __restrict__ hw,
    float* __restrict__ topk_score, float* __restrict__ det_box,
    int* __restrict__ det_label, int* __restrict__ keep, int* __restrict__ nvalid) {
  __shared__ int h[NBUCK];                   // 16KB
  __shared__ int cur[NBUCK];                 // 16KB
  __shared__ ull sk[SORTN];                  // 32KB
  __shared__ int sbs;
  int b = blockIdx.x, tid = threadIdx.x;
#pragma unroll
  for (int k = 0; k < NBUCK / 1024; ++k) h[tid + k * 1024] = 0;
  if (tid == 0) sbs = 0;
  __syncthreads();
  int seg = tid >> 1;                        // 512 segments per image
  int par = tid & 1;
  int gseg = b * BPI + seg;
  int scnt = bcnt[gseg];
  const ull* sptr = dense + (size_t)gseg * BCAP;
  // pass A: histogram
  for (int j = par; j < scnt; j += 2)
    atomicAdd(&h[score_bucket((unsigned)(sptr[j] >> 32))], 1);
  __syncthreads();
  // inclusive suffix scan: h[i] = count in buckets >= i
  for (int d = 1; d < NBUCK; d <<= 1) {
    int v[NBUCK / 1024];
#pragma unroll
    for (int k = 0; k < NBUCK / 1024; ++k) {
      int i = tid + k * 1024;
      v[k] = h[i] + ((i + d < NBUCK) ? h[i + d] : 0);
    }
    __syncthreads();
#pragma unroll
    for (int k = 0; k < NBUCK / 1024; ++k) h[tid + k * 1024] = v[k];
    __syncthreads();
  }
#pragma unroll
  for (int k = 0; k < NBUCK / 1024; ++k) {
    int i = tid + k * 1024;
    if (h[i] >= KTOP && (i == NBUCK - 1 || h[i + 1] < KTOP)) sbs = i;
  }
  __syncthreads();
#pragma unroll
  for (int k = 0; k < NBUCK / 1024; ++k) {
    int i = tid + k * 1024;
    cur[i] = (i + 1 < NBUCK) ? h[i + 1] : 0;   // region starts -> working cursors
  }
  __syncthreads();
  int sb = sbs;
  int total = min(h[sb], SORTN);
  // pass B: scatter survivors into sk at per-bucket LDS cursors
  for (int j = par; j < scnt; j += 2) {
    ull key = sptr[j];
    int bk = score_bucket((unsigned)(key >> 32));
    if (bk < sb) continue;
    int pos = atomicAdd(&cur[bk], 1);
    if (pos < SORTN) sk[pos] = key;
  }
  __syncthreads();
  // segmented rank + decode + keep init
  float Hf = (float)hw[0], Wf = (float)hw[1];
  for (int i = tid; i < total; i += 1024) {
    ull key = sk[i];
    int bk = score_bucket((unsigned)(key >> 32));
    int s0 = (bk + 1 < NBUCK) ? h[bk + 1] : 0;
    int e = min(cur[bk], total);
    int r = s0;
    for (int j = s0; j < e; ++j) r += (sk[j] > key) ? 1 : 0;
    if (r < KTOP) {
      int og = b * KTOP + r;
      topk_score[og] = __uint_as_float((unsigned)(key >> 32));
      int fidx = (int)(~(unsigned)key);
      int p = fidx / (NC - 1), c = fidx % (NC - 1) + 1;
      float4 pr = reinterpret_cast<const float4*>(props)[b * NP + p];
      float4 rel =
          reinterpret_cast<const float4*>(boxreg + (size_t)(b * NP + p) * 4 * NC)[c];
      float x1, y1, x2, y2;
      decode_box(pr, rel, Wf, Hf, x1, y1, x2, y2);
      det_box[(size_t)og * 4 + 0] = x1;
      det_box[(size_t)og * 4 + 1] = y1;
      det_box[(size_t)og * 4 + 2] = x2;
      det_box[(size_t)og * 4 + 3] = y2;
      det_label[og] = c;
      keep[og] = 1;
    }
  }
  int valid_n = min(total, KTOP);
  for (int r = valid_n + tid; r < KTOP; r += 1024) {
    int og = b * KTOP + r;
    topk_score[og] = NEGV;
    det_box[(size_t)og * 4 + 0] = 0.0f;
    det_box[(size_t)og * 4 + 1] = 0.0f;
    det_box[(size_t)og * 4 + 2] = 0.0f;
    det_box[(size_t)og * 4 + 3] = 0.0f;
    det_label[og] = 0;
    keep[og] = 0;
  }
  if (tid == 0) nvalid[b] = valid_n;
}

// WIDE per-(image,label) greedy NMS: 720 one-wave blocks (verbatim R15/R17).
__global__ __launch_bounds__(64) void k_nms(
    const int* __restrict__ nvalid, const float* __restrict__ det_box,
    const int* __restrict__ det_label, int* __restrict__ keep) {
  __shared__ int list[MROWS];
  __shared__ float4 mbx[64];
  __shared__ unsigned char sup[MROWS];
  int bb = blockIdx.x;
  int b = bb / NLAB;
  int lab = bb % NLAB + 1;
  int lane = threadIdx.x;
  int nv = nvalid[b];
  ull below = (1ull << lane) - 1ull;
  const int* ll = det_label + b * KTOP;
  int c = 0;
  for (int base = 0; base < KTOP; base += 64) {
    int i = base + lane;
    bool mb = (i < KTOP) && (i < nv) && (ll[i] == lab);
    ull bal = __ballot(mb);
    if (mb) list[c + __popcll(bal & below)] = i;
    c += __popcll(bal);
  }
  if (c <= 1) return;
  __syncthreads();
  const float4* bbx = reinterpret_cast<const float4*>(det_box) + (size_t)b * KTOP;
  if (c <= 64) {
    if (lane < c) mbx[lane] = bbx[list[lane]];
    __syncthreads();
    float4 bx = mbx[(lane < c) ? lane : 0];
    float area = (bx.z - bx.x) * (bx.w - bx.y);
    ull col = 0ull;
    for (int i = 0; i + 1 < c; ++i) {
      float4 bi = mbx[i];                      // uniform -> broadcast, independent
      float ai = (bi.z - bi.x) * (bi.w - bi.y);
      float ltx = fmaxf(bi.x, bx.x), lty = fmaxf(bi.y, bx.y);
      float rbx = fminf(bi.z, bx.z), rby = fminf(bi.w, bx.w);
      float iw = fmaxf(rbx - ltx, 0.0f), ih = fmaxf(rby - lty, 0.0f);
      float inter = iw * ih;
      float iou = inter / (ai + area - inter + 1e-9f);
      if ((lane > i) && (lane < c) && (iou > NMS_T)) col |= (1ull << i);
    }
    if (__ballot(col != 0ull)) {
      unsigned s = 0u;
      for (int i = 0; i + 1 < c; ++i) {
        ull act = __ballot(s == 0u);           // bit i final at step i
        s |= (unsigned)((act >> i) & (col >> i) & 1ull);
      }
      if (lane < c && s) keep[b * KTOP + list[lane]] = 0;
    }
  } else {
    // pathological big group: ordered serial greedy on lane 0 (rarely hit)
    if (lane == 0) {
      for (int a = 0; a < c; ++a) sup[a] = 0;
      for (int a = 0; a < c; ++a) {
        if (sup[a]) continue;
        float4 bi = bbx[list[a]];
        float ai = (bi.z - bi.x) * (bi.w - bi.y);
        for (int e = a + 1; e < c; ++e) {
          if (sup[e]) continue;
          float4 bj = bbx[list[e]];
          float aj = (bj.z - bj.x) * (bj.w - bj.y);
          float ltx = fmaxf(bi.x, bj.x), lty = fmaxf(bi.y, bj.y);
          float rbx = fminf(bi.z, bj.z), rby = fminf(bi.w, bj.w);
          float iw = fmaxf(rbx - ltx, 0.0f), ih = fmaxf(rby - lty, 0.0f);
          float inter = iw * ih;
          if (inter / (ai + aj - inter + 1e-9f) > NMS_T) sup[e] = 1;
        }
      }
      for (int a = 0; a < c; ++a)
        if (sup[a]) keep[b * KTOP + list[a]] = 0;
    }
  }
}

// Final emit (8 blocks, verbatim): prefix scan of keep, first 100 kept in
// score order -> out, zero-pad the rest.
__global__ __launch_bounds__(256) void k_output(
    const float* __restrict__ topk_score, const float* __restrict__ det_box,
    const int* __restrict__ det_label, const int* __restrict__ keep,
    float* __restrict__ out) {
  __shared__ int kp[MROWS];
  __shared__ int pf[MROWS];
  int b = blockIdx.x, tid = threadIdx.x;
  for (int i = tid; i < MROWS; i += 256) {
    int v = (i < KTOP) ? keep[b * KTOP + i] : 0;
    kp[i] = v;
    pf[i] = v;
  }
  __syncthreads();
  for (int d = 1; d < MROWS; d <<= 1) {
    int v[4];
#pragma unroll
    for (int k = 0; k < 4; ++k) {
      int i = tid + k * 256;
      v[k] = pf[i] + ((i >= d) ? pf[i - d] : 0);
    }
    __syncthreads();
#pragma unroll
    for (int k = 0; k < 4; ++k) pf[tid + k * 256] = v[k];
    __syncthreads();
  }
  int total = min(pf[KTOP - 1], NDET);
  float* ob = out;
  float* os = out + (size_t)NB * NDET * 4;
  float* ol = os + (size_t)NB * NDET;
  for (int i = tid; i < KTOP; i += 256) {
    if (kp[i]) {
      int r = pf[i] - 1;
      if (r < NDET) {
        ob[((size_t)b * NDET + r) * 4 + 0] = det_box[((size_t)b * KTOP + i) * 4 + 0];
        ob[((size_t)b * NDET + r) * 4 + 1] = det_box[((size_t)b * KTOP + i) * 4 + 1];
        ob[((size_t)b * NDET + r) * 4 + 2] = det_box[((size_t)b * KTOP + i) * 4 + 2];
        ob[((size_t)b * NDET + r) * 4 + 3] = det_box[((size_t)b * KTOP + i) * 4 + 3];
        os[b * NDET + r] = topk_score[b * KTOP + i];
        ol[b * NDET + r] = (float)det_label[b * KTOP + i];
      }
    }
  }
  for (int r = total + tid; r < NDET; r += 256) {
    ob[((size_t)b * NDET + r) * 4 + 0] = 0.0f;
    ob[((size_t)b * NDET + r) * 4 + 1] = 0.0f;
    ob[((size_t)b * NDET + r) * 4 + 2] = 0.0f;
    ob[((size_t)b * NDET + r) * 4 + 3] = 0.0f;
    os[b * NDET + r] = 0.0f;
    ol[b * NDET + r] = 0.0f;
  }
}

}  // namespace

extern "C" void kernel_launch(void* const* d_in, const int* in_sizes, int n_in,
                              void* d_out, int out_size, void* d_ws, size_t ws_size,
                              hipStream_t stream) {
  const float* logits = (const float*)d_in[0];
  const float* boxreg = (const float*)d_in[1];
  const float* props = (const float*)d_in[2];
  const int* hw = (const int*)d_in[3];

  char* ws = (char*)d_ws;
  size_t off = 0;
  auto alloc = [&](size_t bytes) -> void* {
    void* p = ws + off;
    off += (bytes + 255) & ~(size_t)255;
    return p;
  };
  ull* dense = (ull*)alloc((size_t)NB * BPI * BCAP * 8);
  int* bcnt = (int*)alloc((size_t)NB * BPI * 4);
  float* topk_score = (float*)alloc((size_t)NB * KTOP * 4);
  float* det_box = (float*)alloc((size_t)NB * KTOP * 16);
  int* det_label = (int*)alloc((size_t)NB * KTOP * 4);
  int* keep = (int*)alloc((size_t)NB * KTOP * 4);
  int* nvalid = (int*)alloc(NB * 4);

  k_candidates<<<(NB * NP) / 16, 256, 0, stream>>>(logits, boxreg, props, hw,
                                                   dense, bcnt);
  k_select<<<NB, 1024, 0, stream>>>(dense, bcnt, boxreg, props, hw,
                                    topk_score, det_box, det_label, keep, nvalid);
  k_nms<<<NB * NLAB, 64, 0, stream>>>(nvalid, det_box, det_label, keep);
  k_output<<<NB, 256, 0, stream>>>(topk_score, det_box, det_label, keep, (float*)d_out);
}